// Round 1
// 1125.485 us; speedup vs baseline: 1.0207x; 1.0207x over previous
//
#include <hip/hip_runtime.h>

// Fused irreps lifting TP: one block = TM=16 rows of x (576 f32, read contiguously)
// -> same 16 rows of out (2304 f32, written contiguously).
// Per l (d=2l+1): out[n, OFF_OUT + w*d + i] = (1/8) * sum_u x[n, OFF_IN + u*d + i] * W_l[u][w]

typedef __attribute__((ext_vector_type(8))) short bf16x8;   // 8 bf16 = 4 VGPRs
typedef __attribute__((ext_vector_type(4))) float f32x4;

__device__ __forceinline__ unsigned short f2bf(float f) {
  // fp32 -> bf16 round-to-nearest-even (inputs are finite normals)
  union { float f; unsigned u; } a; a.f = f;
  unsigned r = a.u + 0x7fffu + ((a.u >> 16) & 1u);
  return (unsigned short)(r >> 16);
}

constexpr int SP    = 72;      // LDS A row stride in bf16 (144 B rows, 16B-aligned, non-pow2 bank stride)
constexpr int TM    = 16;      // rows per block
constexpr int AROWS = TM * 9;  // 144 A rows: l0 ar=ln (16), l1 ar=16+ln*3+i (48), l2 ar=64+ln*5+i (80)

template<int D, int AROW0, int OFF_OUT>
__device__ __forceinline__ void process_l(const float* __restrict__ W,
                                          const unsigned short* sa, float* sc,
                                          float* __restrict__ out, int n_total, int n0,
                                          int tid, int wv, int quad, int nc) {
  // ---- B fragments: B[k=u][w], k = s*32 + quad*8 + j, w = wv*64 + t*16 + nc (W is L2-resident) ----
  bf16x8 bfrag[4][2];
#pragma unroll
  for (int t = 0; t < 4; ++t)
#pragma unroll
    for (int s = 0; s < 2; ++s) {
      const int w = wv * 64 + t * 16 + nc;
#pragma unroll
      for (int j = 0; j < 8; ++j)
        bfrag[t][s][j] = (short)f2bf(W[(s * 32 + quad * 8 + j) * 256 + w]);
    }

  f32x4 acc[D][4];
#pragma unroll
  for (int r = 0; r < D; ++r)
#pragma unroll
    for (int t = 0; t < 4; ++t)
      acc[r][t] = (f32x4){0.f, 0.f, 0.f, 0.f};

  // ---- MFMA: rows m = r*16 + (lane&15), K = 64 split in two K=32 halves ----
#pragma unroll
  for (int r = 0; r < D; ++r)
#pragma unroll
    for (int s = 0; s < 2; ++s) {
      const bf16x8 af = *(const bf16x8*)(sa + (AROW0 + r * 16 + nc) * SP + s * 32 + quad * 8);
#pragma unroll
      for (int t = 0; t < 4; ++t)
        acc[r][t] = __builtin_amdgcn_mfma_f32_16x16x32_bf16(af, bfrag[t][s], acc[r][t], 0, 0, 0);
    }

  // ---- epilogue: 4 phases over 64-wide w chunks; wave ch stages its chunk, all waves store ----
#pragma unroll
  for (int ch = 0; ch < 4; ++ch) {
    __syncthreads();                       // protects sc from the previous phase's readers
    if (wv == ch) {
#pragma unroll
      for (int r = 0; r < D; ++r)
#pragma unroll
        for (int t = 0; t < 4; ++t) {
          const int wl = t * 16 + nc;      // 0..63 within this wave's chunk
#pragma unroll
          for (int reg = 0; reg < 4; ++reg) {
            const int m = r * 16 + quad * 4 + reg;   // C row = quad*4 + reg (m89 layout)
            sc[((m / D) * 64 + wl) * D + (m % D)] = acc[r][t][reg] * 0.125f;
          }
        }
    }
    __syncthreads();
    // contiguous f32x4 nontemporal stores: out[n, OFF_OUT + ch*64*D + (wl*D+i)]
#pragma unroll
    for (int it = 0; it < D; ++it) {
      const int F  = (tid + it * 256) * 4;
      const int ln = F / (64 * D);
      const int p  = F % (64 * D);
      const int n  = n0 + ln;
      if (n < n_total)
        __builtin_nontemporal_store(*(const f32x4*)(sc + F),
                                    (f32x4*)(out + (size_t)n * 2304 + OFF_OUT + ch * 64 * D + p));
    }
  }
}

__launch_bounds__(256, 3)   // 3 blocks/CU: LDS 41.2 KB/block, VGPR cap ~170 (acc 80 + bfrag 32 fits)
__global__ void tp_fused(const float* __restrict__ x,
                         const float* __restrict__ W0, const float* __restrict__ W1,
                         const float* __restrict__ W2,
                         float* __restrict__ out, int n_total) {
  __shared__ __align__(16) unsigned short sa[AROWS * SP]; // 20736 B: transposed bf16 A, all 3 l's
  __shared__ __align__(16) float sc[TM * 64 * 5];         // 20480 B: C staging, one w-chunk (D=5 worst)

  const int tid  = threadIdx.x;
  const int wv   = tid >> 6;
  const int lane = tid & 63;
  const int quad = lane >> 4;
  const int nc   = lane & 15;
  const int n0   = blockIdx.x * TM;

  // ---- stage: full 576-f32 rows, dense coalesced f32x4 reads -> bf16 LDS, (u,i)-transposed.
  // l-boundaries (64, 256) are multiples of 4, so each f32x4 lies in exactly one l region.
#pragma unroll
  for (int it = 0; it < 9; ++it) {                 // 16*576/4/256 = 9
    const int F  = (tid + it * 256) * 4;           // 0..9215 (flat f32 index in the block's x tile)
    const int ln = F / 576;
    const int e  = F % 576;
    const int n  = n0 + ln;
    f32x4 v = {0.f, 0.f, 0.f, 0.f};
    if (n < n_total)
      v = __builtin_nontemporal_load((const f32x4*)(x + (size_t)n * 576 + e));
    if (e < 64) {                                  // l=0: u=e, i=0
#pragma unroll
      for (int k = 0; k < 4; ++k)
        sa[ln * SP + (e + k)] = f2bf(v[k]);
    } else if (e < 256) {                          // l=1: d=3
#pragma unroll
      for (int k = 0; k < 4; ++k) {
        const int ee = e - 64 + k;
        sa[(16 + ln * 3 + (ee % 3)) * SP + (ee / 3)] = f2bf(v[k]);
      }
    } else {                                       // l=2: d=5
#pragma unroll
      for (int k = 0; k < 4; ++k) {
        const int ee = e - 256 + k;
        sa[(64 + ln * 5 + (ee % 5)) * SP + (ee / 5)] = f2bf(v[k]);
      }
    }
  }
  __syncthreads();

  process_l<1,  0,    0>(W0, sa, sc, out, n_total, n0, tid, wv, quad, nc);
  process_l<3, 16,  256>(W1, sa, sc, out, n_total, n0, tid, wv, quad, nc);
  process_l<5, 64, 1024>(W2, sa, sc, out, n_total, n0, tid, wv, quad, nc);
}

extern "C" void kernel_launch(void* const* d_in, const int* in_sizes, int n_in,
                              void* d_out, int out_size, void* d_ws, size_t ws_size,
                              hipStream_t stream) {
  const float* x  = (const float*)d_in[0];
  const float* W0 = (const float*)d_in[1];
  const float* W1 = (const float*)d_in[2];
  const float* W2 = (const float*)d_in[3];
  float* out = (float*)d_out;
  const int n = in_sizes[0] / 576;

  tp_fused<<<(n + TM - 1) / TM, 256, 0, stream>>>(x, W0, W1, W2, out, n);
}